// Round 8
// baseline (386.797 us; speedup 1.0000x reference)
//
#include <hip/hip_runtime.h>

#define N_NODE 80000
#define N_NET  20000
#define NE     150000
#define WLN    17408   // 34 c2h-steps * 512 u16 (64 lanes * 8 bf16) per relation
#define NB     586     // ceil(NE/256)

typedef unsigned short u16;
typedef unsigned int u32;
typedef __attribute__((ext_vector_type(8))) short short8v;
typedef __attribute__((ext_vector_type(4))) float f32x4;

static __device__ __forceinline__ u16 f2bf(float f) {
  u32 x = __float_as_uint(f);
  x += 0x7fffu + ((x >> 16) & 1u);   // round-to-nearest-even
  return (u16)(x >> 16);
}

// W' tables in exact MFMA B-fragment lane order.  Half h -> ADJACENT output
// pairs: o = 2*o' + h (o' = lane&15), so each lane's two accumulators are
// output cols (2o', 2o'+1) -> one float2 store per D register.
//   WL[(c*2+h)*512 + lane*8 + j] = W'[(c, kg*8+j), 2*(lane&15)+h]
//   W'[(k,i),o] = W[(i*32+o)*16 + k] for k<16;  = b[i*32+o] for k==16 (bias).
__global__ __launch_bounds__(256) void wprep_kernel(
    const float* __restrict__ topo_w, const float* __restrict__ topo_b,
    const float* __restrict__ geom_w, const float* __restrict__ geom_b,
    u16* __restrict__ WL0, u16* __restrict__ WL1) {
  int idx = blockIdx.x * 256 + threadIdx.x;   // 2*17408 = 34816 exact
  int rel = idx / WLN;
  int g = idx % WLN;
  int c2h = g >> 9, l = (g >> 3) & 63, j = g & 7;
  int op = l & 15, kg = l >> 4, c = c2h >> 1, h = c2h & 1;
  int i = kg * 8 + j, o = 2 * op + h;
  const float* w = rel ? geom_w : topo_w;
  const float* b = rel ? geom_b : topo_b;
  float v = (c < 16) ? w[(i * 32 + o) * 16 + c] : b[i * 32 + o];
  (rel ? WL1 : WL0)[g] = f2bf(v);
}

// Integer degree histograms (u32 atomics: cheap, exact, proven-native).
__global__ __launch_bounds__(256) void hist_kernel(
    const int* __restrict__ pins_src, const int* __restrict__ pins_dst,
    const int* __restrict__ pinned_dst, const int* __restrict__ near_dst,
    u32* __restrict__ hN, u32* __restrict__ hP, u32* __restrict__ hNr,
    u32* __restrict__ hS) {
  int e = blockIdx.x * 256 + threadIdx.x;
  if (e >= NE) return;
  atomicAdd(&hN[pins_dst[e]], 1u);
  atomicAdd(&hP[pinned_dst[e]], 1u);
  atomicAdd(&hNr[near_dst[e]], 1u);
  atomicAdd(&hS[pins_src[e]], 1u);
}

// Exclusive prefix scan of 3 histograms (one block each); writes row_ptr
// (n+1 entries) and an identical cursor copy for the perm-build scatter.
__global__ __launch_bounds__(1024) void scan_kernel(
    const u32* __restrict__ hN, u32* __restrict__ rpN, u32* __restrict__ curN,
    const u32* __restrict__ hP, u32* __restrict__ rpP, u32* __restrict__ curP,
    const u32* __restrict__ hNr, u32* __restrict__ rpNr, u32* __restrict__ curNr) {
  const u32* h; u32 *rp, *cur; int n;
  if (blockIdx.x == 0)      { h = hN;  rp = rpN;  cur = curN;  n = N_NET; }
  else if (blockIdx.x == 1) { h = hP;  rp = rpP;  cur = curP;  n = N_NODE; }
  else                      { h = hNr; rp = rpNr; cur = curNr; n = N_NODE; }
  int t = threadIdx.x;
  int chunk = (n + 1023) / 1024;
  int lo = t * chunk, hi = min(lo + chunk, n);
  u32 s = 0;
  for (int i = lo; i < hi; ++i) s += h[i];
  __shared__ u32 ps[1024];
  ps[t] = s;
  __syncthreads();
  for (int d = 1; d < 1024; d <<= 1) {   // Hillis-Steele inclusive scan
    u32 v = (t >= d) ? ps[t - d] : 0u;
    __syncthreads();
    ps[t] += v;
    __syncthreads();
  }
  u32 r = (t == 0) ? 0u : ps[t - 1];
  for (int i = lo; i < hi; ++i) { rp[i] = r; cur[i] = r; r += h[i]; }
  if (t == 1023) rp[n] = ps[1023];
}

// Scatter edges into dst-sorted order. pins stores the SRC id (all the net
// gather needs); pinned/near store the edge id (for pf + src gathers).
__global__ __launch_bounds__(256) void perm_kernel(
    const int* __restrict__ pins_src, const int* __restrict__ pins_dst,
    const int* __restrict__ pinned_dst, const int* __restrict__ near_dst,
    u32* __restrict__ curN, u32* __restrict__ curP, u32* __restrict__ curNr,
    u32* __restrict__ permS, u32* __restrict__ permP, u32* __restrict__ permN) {
  int rel = blockIdx.x / NB;
  int e = (blockIdx.x % NB) * 256 + threadIdx.x;
  if (e >= NE) return;
  if (rel == 0)      { u32 p = atomicAdd(&curN[pins_dst[e]], 1u);  permS[p] = (u32)pins_src[e]; }
  else if (rel == 1) { u32 p = atomicAdd(&curP[pinned_dst[e]], 1u);  permP[p] = (u32)e; }
  else               { u32 p = atomicAdd(&curNr[near_dst[e]], 1u); permN[p] = (u32)e; }
}

// NNConv direct-MFMA over dst-sorted edges: per 16-edge tile, 17 MFMA steps.
// A[e, c*32+i] = pf[e,c] * feat[src_e, i]  (c=16 = bias step, pf=1).
// D (m89): col=lane&15, row=(lane>>4)*4+r = tile-row.  o=2o'+h W-layout ->
// lane holds cols (2er, 2er+1) of row kg*4+r in (a0[r], a1[r]) -> ONE float2
// PLAIN STORE per r to msg[sorted_pos][2er..]: 16 rows x 128B contiguous per
// wave instruction. No atomics anywhere in this kernel.
__global__ __launch_bounds__(512) void nnconv_mfma_kernel(
    const float* __restrict__ feat0, const float* __restrict__ ef0,
    const int* __restrict__ src0, const u32* __restrict__ perm0,
    const u16* __restrict__ WL0, float* __restrict__ msg0,
    const float* __restrict__ feat1, const float* __restrict__ ef1,
    const int* __restrict__ src1, const u32* __restrict__ perm1,
    const u16* __restrict__ WL1, float* __restrict__ msg1,
    int nb0) {
  __shared__ u16 WS[WLN];
  bool rel = blockIdx.x >= nb0;
  int b = rel ? blockIdx.x - nb0 : blockIdx.x;
  const float* feat = rel ? feat1 : feat0;
  const float* ef   = rel ? ef1 : ef0;
  const int* srcp   = rel ? src1 : src0;
  const u32* perm   = rel ? perm1 : perm0;
  const u16* WLg    = rel ? WL1 : WL0;
  float* msg        = rel ? msg1 : msg0;

  for (int t = threadIdx.x; t < WLN / 8; t += 512)
    ((uint4*)WS)[t] = ((const uint4*)WLg)[t];
  __syncthreads();

  int w = threadIdx.x >> 6, lane = threadIdx.x & 63;
  int er = lane & 15, kg = lane >> 4;

#pragma unroll
  for (int it = 0; it < 2; ++it) {
    int tt = b * 16 + w * 2 + it;          // 16 tiles per block, 2 per wave
    if (tt >= 9375) continue;              // 150000/16 = 9375 exact tiles
    int e0 = tt * 16;
    int e = (int)perm[e0 + er];            // this lane's edge (dst-sorted order)
    int s = srcp[e];
    const float* fp = feat + (size_t)s * 32 + kg * 8;
    float4 f0 = *(const float4*)fp;
    float4 f1 = *(const float4*)(fp + 4);
    float4 pq = *(const float4*)(ef + (size_t)e * 16 + kg * 4);  // pf[er, kg*4..+4]
    f32x4 a0 = {0.f, 0.f, 0.f, 0.f}, a1 = {0.f, 0.f, 0.f, 0.f};
#pragma unroll
    for (int c = 0; c < 16; ++c) {
      int srcl = er + 16 * (c >> 2);
      float pc = (c & 3) == 0 ? pq.x : (c & 3) == 1 ? pq.y : (c & 3) == 2 ? pq.z : pq.w;
      float pv = __shfl(pc, srcl, 64);     // = pf[tile-row er, c]
      u32 d0, d1, d2, d3;
      asm("v_cvt_pk_bf16_f32 %0, %1, %2" : "=v"(d0) : "v"(pv * f0.x), "v"(pv * f0.y));
      asm("v_cvt_pk_bf16_f32 %0, %1, %2" : "=v"(d1) : "v"(pv * f0.z), "v"(pv * f0.w));
      asm("v_cvt_pk_bf16_f32 %0, %1, %2" : "=v"(d2) : "v"(pv * f1.x), "v"(pv * f1.y));
      asm("v_cvt_pk_bf16_f32 %0, %1, %2" : "=v"(d3) : "v"(pv * f1.z), "v"(pv * f1.w));
      short8v af;
      ((u32*)&af)[0] = d0; ((u32*)&af)[1] = d1; ((u32*)&af)[2] = d2; ((u32*)&af)[3] = d3;
      short8v b0 = *(const short8v*)(WS + (c * 2 + 0) * 512 + lane * 8);
      short8v b1 = *(const short8v*)(WS + (c * 2 + 1) * 512 + lane * 8);
      a0 = __builtin_amdgcn_mfma_f32_16x16x32_bf16(af, b0, a0, 0, 0, 0);
      a1 = __builtin_amdgcn_mfma_f32_16x16x32_bf16(af, b1, a1, 0, 0, 0);
    }
    {  // bias step c=16: A = feat (pf == 1)
      u32 d0, d1, d2, d3;
      asm("v_cvt_pk_bf16_f32 %0, %1, %2" : "=v"(d0) : "v"(f0.x), "v"(f0.y));
      asm("v_cvt_pk_bf16_f32 %0, %1, %2" : "=v"(d1) : "v"(f0.z), "v"(f0.w));
      asm("v_cvt_pk_bf16_f32 %0, %1, %2" : "=v"(d2) : "v"(f1.x), "v"(f1.y));
      asm("v_cvt_pk_bf16_f32 %0, %1, %2" : "=v"(d3) : "v"(f1.z), "v"(f1.w));
      short8v af;
      ((u32*)&af)[0] = d0; ((u32*)&af)[1] = d1; ((u32*)&af)[2] = d2; ((u32*)&af)[3] = d3;
      short8v b0 = *(const short8v*)(WS + 32 * 512 + lane * 8);
      short8v b1 = *(const short8v*)(WS + 33 * 512 + lane * 8);
      a0 = __builtin_amdgcn_mfma_f32_16x16x32_bf16(af, b0, a0, 0, 0, 0);
      a1 = __builtin_amdgcn_mfma_f32_16x16x32_bf16(af, b1, a1, 0, 0, 0);
    }
#pragma unroll
    for (int r = 0; r < 4; ++r) {
      int pos = e0 + kg * 4 + r;           // sorted position of this row
      *(float2*)(msg + (size_t)pos * 32 + er * 2) = make_float2(a0[r], a1[r]);
    }
  }
}

// pins aggregation via CSR gather: agg[m] = sum over its edges of
// norm_src[s]*node_feat[s].  16 threads per net own output pairs; the 16
// threads read the same node_feat row -> coalesced 128B per j.
__global__ __launch_bounds__(256) void agg_gather_kernel(
    const float* __restrict__ node_feat, const u32* __restrict__ permS,
    const u32* __restrict__ rpN, const u32* __restrict__ hS,
    float* __restrict__ agg) {
  int gid = blockIdx.x * 256 + threadIdx.x;
  int m = gid >> 4;
  if (m >= N_NET) return;
  int p = gid & 15;
  u32 j0 = rpN[m], j1 = rpN[m + 1];
  float ax = 0.f, ay = 0.f;
  for (u32 j = j0; j < j1; ++j) {
    int s = (int)permS[j];
    float ns = rsqrtf(fmaxf((float)hS[s], 1.0f));
    float2 nf = *(const float2*)(node_feat + (size_t)s * 32 + p * 2);
    ax += ns * nf.x; ay += ns * nf.y;
  }
  *(float2*)(agg + (size_t)m * 32 + p * 2) = make_float2(ax, ay);
}

// net_out = rsqrt(max(deg_in,1)) * (agg @ gc_w) + gc_b;  deg_in from row_ptr.
__global__ __launch_bounds__(256) void net_out_kernel(
    const float* __restrict__ agg, const u32* __restrict__ rpN,
    const float* __restrict__ gc_w, const float* __restrict__ gc_b,
    float* __restrict__ out) {
  int gid = blockIdx.x * 256 + threadIdx.x;
  int m = gid >> 5;
  if (m >= N_NET) return;
  int o = gid & 31;
  float nd = rsqrtf(fmaxf((float)(rpN[m + 1] - rpN[m]), 1.0f));
  const float* ag = agg + (size_t)m * 32;
  float a = 0.f;
#pragma unroll
  for (int j = 0; j < 32; ++j) a += ag[j] * gc_w[j * 32 + o];
  out[(size_t)N_NODE * 32 + (size_t)m * 32 + o] = a * nd + gc_b[o];
}

// Fused segmented mean + bias + max: each node's messages are contiguous in
// msg_p/msg_n (dst-sorted).  16 threads per node own output pairs; reads are
// streaming 128B rows.  deg = row_ptr diff (clamped to 1, DGL mean semantics).
__global__ __launch_bounds__(256) void node_out_kernel(
    const float* __restrict__ msg_p, const float* __restrict__ msg_n,
    const u32* __restrict__ rpP, const u32* __restrict__ rpNr,
    const float* __restrict__ pinned_b, const float* __restrict__ near_b,
    float* __restrict__ out) {
  int gid = blockIdx.x * 256 + threadIdx.x;   // N_NODE*16
  int v = gid >> 4;
  if (v >= N_NODE) return;
  int p = gid & 15;
  u32 a0 = rpP[v], a1 = rpP[v + 1];
  float px = 0.f, py = 0.f;
  for (u32 j = a0; j < a1; ++j) {
    float2 mm = *(const float2*)(msg_p + (size_t)j * 32 + p * 2);
    px += mm.x; py += mm.y;
  }
  float idp = 1.0f / fmaxf((float)(a1 - a0), 1.0f);
  u32 b0 = rpNr[v], b1 = rpNr[v + 1];
  float nx = 0.f, ny = 0.f;
  for (u32 j = b0; j < b1; ++j) {
    float2 mm = *(const float2*)(msg_n + (size_t)j * 32 + p * 2);
    nx += mm.x; ny += mm.y;
  }
  float idn = 1.0f / fmaxf((float)(b1 - b0), 1.0f);
  float2 r;
  r.x = fmaxf(px * idp + pinned_b[2 * p],     nx * idn + near_b[2 * p]);
  r.y = fmaxf(py * idp + pinned_b[2 * p + 1], ny * idn + near_b[2 * p + 1]);
  *(float2*)(out + (size_t)v * 32 + p * 2) = r;
}

extern "C" void kernel_launch(void* const* d_in, const int* in_sizes, int n_in,
                              void* d_out, int out_size, void* d_ws, size_t ws_size,
                              hipStream_t stream) {
  const float* node_feat = (const float*)d_in[0];
  const float* net_feat  = (const float*)d_in[1];
  const float* pin_feat  = (const float*)d_in[2];
  const float* edge_feat = (const float*)d_in[3];
  const float* topo_w    = (const float*)d_in[4];
  const float* topo_b    = (const float*)d_in[5];
  const float* geom_w    = (const float*)d_in[6];
  const float* geom_b    = (const float*)d_in[7];
  const float* gc_w      = (const float*)d_in[8];
  const float* gc_b      = (const float*)d_in[9];
  const float* pinned_b  = (const float*)d_in[10];
  const float* near_b    = (const float*)d_in[11];
  const int* pins_src    = (const int*)d_in[12];
  const int* pins_dst    = (const int*)d_in[13];
  const int* pinned_src  = (const int*)d_in[14];
  const int* pinned_dst  = (const int*)d_in[15];
  const int* near_src    = (const int*)d_in[16];
  const int* near_dst    = (const int*)d_in[17];

  char* ws = (char*)d_ws;
  float* msg_p = (float*)ws;                 // 4,800,000 f32 (19.2 MB)
  float* msg_n = msg_p + 4800000;            // 4,800,000
  float* agg   = msg_n + 4800000;            //   640,000
  u32* hN   = (u32*)(agg + 640000);          //  20,000  -- zero region start
  u32* hP   = hN + 20000;                    //  80,000
  u32* hNr  = hP + 80000;                    //  80,000
  u32* hS   = hNr + 80000;                   //  80,000  -- zero region end
  u32* rpN  = hS + 80000;                    //  20,001
  u32* rpP  = rpN + 20001;                   //  80,001
  u32* rpNr = rpP + 80001;                   //  80,001
  u32* curN = rpNr + 80001;                  //  20,000
  u32* curP = curN + 20000;                  //  80,000
  u32* curNr= curP + 80000;                  //  80,000
  u32* permS= curNr + 80000;                 // 150,000
  u32* permP= permS + 150000;                // 150,000
  u32* permN= permP + 150000;                // 150,000
  size_t wb = (size_t)((char*)(permN + 150000) - ws);
  wb = (wb + 255) & ~(size_t)255;            // 16B-align WL for uint4 loads
  u16* WL0 = (u16*)(ws + wb);
  u16* WL1 = WL0 + WLN;

  hipMemsetAsync(hN, 0, (size_t)260000 * 4, stream);   // the 4 histograms
  wprep_kernel<<<136, 256, 0, stream>>>(topo_w, topo_b, geom_w, geom_b, WL0, WL1);
  hist_kernel<<<NB, 256, 0, stream>>>(pins_src, pins_dst, pinned_dst, near_dst,
                                      hN, hP, hNr, hS);
  scan_kernel<<<3, 1024, 0, stream>>>(hN, rpN, curN, hP, rpP, curP, hNr, rpNr, curNr);
  perm_kernel<<<3 * NB, 256, 0, stream>>>(pins_src, pins_dst, pinned_dst, near_dst,
                                          curN, curP, curNr, permS, permP, permN);
  nnconv_mfma_kernel<<<2 * NB, 512, 0, stream>>>(
      net_feat,  pin_feat,  pinned_src, permP, WL0, msg_p,
      node_feat, edge_feat, near_src,   permN, WL1, msg_n, NB);
  agg_gather_kernel<<<N_NET * 16 / 256, 256, 0, stream>>>(node_feat, permS, rpN, hS, agg);
  net_out_kernel<<<N_NET * 32 / 256, 256, 0, stream>>>(agg, rpN, gc_w, gc_b, (float*)d_out);
  node_out_kernel<<<N_NODE * 16 / 256, 256, 0, stream>>>(msg_p, msg_n, rpP, rpNr,
                                                         pinned_b, near_b, (float*)d_out);
}

// Round 9
// 240.113 us; speedup vs baseline: 1.6109x; 1.6109x over previous
//
#include <hip/hip_runtime.h>

#define N_NODE 80000
#define N_NET  20000
#define NE     150000
#define WLN    17408   // 34 c2h-steps * 512 u16 (64 lanes * 8 bf16) per relation
#define NB     586     // ceil(NE/256)

typedef unsigned short u16;
typedef unsigned int u32;
typedef __attribute__((ext_vector_type(8))) short short8v;
typedef __attribute__((ext_vector_type(4))) float f32x4;

static __device__ __forceinline__ u16 f2bf(float f) {
  u32 x = __float_as_uint(f);
  x += 0x7fffu + ((x >> 16) & 1u);   // round-to-nearest-even
  return (u16)(x >> 16);
}

// Fused: blocks [0,136) build W' tables; blocks [136,722) histogram degrees.
// W' layout (MFMA B-fragment lane order, half h -> adjacent output pair):
//   WL[(c*2+h)*512 + lane*8 + j] = W'[(c, kg*8+j), 2*(lane&15)+h]
//   W'[(k,i),o] = W[(i*32+o)*16 + k] for k<16;  = b[i*32+o] for k==16 (bias).
__global__ __launch_bounds__(256) void prep_kernel(
    const float* __restrict__ topo_w, const float* __restrict__ topo_b,
    const float* __restrict__ geom_w, const float* __restrict__ geom_b,
    u16* __restrict__ WL0, u16* __restrict__ WL1,
    const int* __restrict__ pins_src, const int* __restrict__ pins_dst,
    const int* __restrict__ pinned_dst, const int* __restrict__ near_dst,
    u32* __restrict__ hN, u32* __restrict__ hP, u32* __restrict__ hNr,
    u32* __restrict__ hS) {
  if (blockIdx.x < 136) {
    int idx = blockIdx.x * 256 + threadIdx.x;   // 2*17408 = 34816 exact
    int rel = idx / WLN;
    int g = idx % WLN;
    int c2h = g >> 9, l = (g >> 3) & 63, j = g & 7;
    int op = l & 15, kg = l >> 4, c = c2h >> 1, h = c2h & 1;
    int i = kg * 8 + j, o = 2 * op + h;
    const float* w = rel ? geom_w : topo_w;
    const float* b = rel ? geom_b : topo_b;
    float v = (c < 16) ? w[(i * 32 + o) * 16 + c] : b[i * 32 + o];
    (rel ? WL1 : WL0)[g] = f2bf(v);
  } else {
    int e = (blockIdx.x - 136) * 256 + threadIdx.x;
    if (e >= NE) return;
    atomicAdd(&hN[pins_dst[e]], 1u);
    atomicAdd(&hP[pinned_dst[e]], 1u);
    atomicAdd(&hNr[near_dst[e]], 1u);
    atomicAdd(&hS[pins_src[e]], 1u);
  }
}

// Atomic chunk allocation replaces the prefix scan (round-8: 3-block scan with
// serial dependent-load loops = 180us at 0.3% occupancy). Each wave
// shuffle-scans 64 degrees, lane 0 grabs a range with ONE atomicAdd on the
// relation counter (~2.8K atomics total), threads derive start[v]. Node order
// in the msg buffer becomes arbitrary -- nothing downstream needs order, only
// per-dst contiguity: segment = [start[v], start[v]+h[v]).
__global__ __launch_bounds__(256) void alloc_kernel(
    const u32* __restrict__ hN, u32* __restrict__ stN, u32* __restrict__ curN,
    const u32* __restrict__ hP, u32* __restrict__ stP, u32* __restrict__ curP,
    const u32* __restrict__ hNr, u32* __restrict__ stNr, u32* __restrict__ curNr,
    u32* __restrict__ cnt) {
  int b = blockIdx.x;
  const u32* h; u32 *st, *cur, *c; int n, v0;
  if (b < 79)       { h = hN;  st = stN;  cur = curN;  c = cnt;     n = N_NET;  v0 = b * 256; }
  else if (b < 392) { h = hP;  st = stP;  cur = curP;  c = cnt + 1; n = N_NODE; v0 = (b - 79) * 256; }
  else              { h = hNr; st = stNr; cur = curNr; c = cnt + 2; n = N_NODE; v0 = (b - 392) * 256; }
  int v = v0 + threadIdx.x;
  int lane = threadIdx.x & 63;
  u32 deg = (v < n) ? h[v] : 0u;
  u32 inc = deg;
#pragma unroll
  for (int d = 1; d < 64; d <<= 1) {
    u32 t = __shfl_up(inc, d, 64);
    if (lane >= d) inc += t;
  }
  u32 total = __shfl(inc, 63, 64);
  u32 base = 0;
  if (lane == 0) base = atomicAdd(c, total);
  base = __shfl(base, 0, 64);
  if (v < n) { u32 s0 = base + inc - deg; st[v] = s0; cur[v] = s0; }
}

// Scatter edges into dst-contiguous order. pins stores the SRC id (all the
// net gather needs); pinned/near store the edge id (for pf + src gathers).
__global__ __launch_bounds__(256) void perm_kernel(
    const int* __restrict__ pins_src, const int* __restrict__ pins_dst,
    const int* __restrict__ pinned_dst, const int* __restrict__ near_dst,
    u32* __restrict__ curN, u32* __restrict__ curP, u32* __restrict__ curNr,
    u32* __restrict__ permS, u32* __restrict__ permP, u32* __restrict__ permN) {
  int rel = blockIdx.x / NB;
  int e = (blockIdx.x % NB) * 256 + threadIdx.x;
  if (e >= NE) return;
  if (rel == 0)      { u32 p = atomicAdd(&curN[pins_dst[e]], 1u);   permS[p] = (u32)pins_src[e]; }
  else if (rel == 1) { u32 p = atomicAdd(&curP[pinned_dst[e]], 1u); permP[p] = (u32)e; }
  else               { u32 p = atomicAdd(&curNr[near_dst[e]], 1u);  permN[p] = (u32)e; }
}

// Blocks [0,2NB): NNConv direct-MFMA over dst-sorted edges (16-edge tiles,
// 17 MFMA steps, K=32; A[e,c*32+i] = pf[e,c]*feat[src_e,i], c=16 bias step).
// D (m89): col=lane&15, row=(lane>>4)*4+r.  o=2o'+h W-layout -> lane holds
// cols (2er,2er+1) of row kg*4+r in (a0[r],a1[r]) -> one float2 plain store
// per r: 16 rows x 128B contiguous per wave instr.  No atomics.
// Blocks [2NB, 2NB+625): pins CSR gather (independent work, fills tail CUs):
// agg[m] = sum_{edges} rsqrt(deg_out[s])*node_feat[s].
__global__ __launch_bounds__(512) void nnconv_agg_kernel(
    const float* __restrict__ feat0, const float* __restrict__ ef0,
    const int* __restrict__ src0, const u32* __restrict__ perm0,
    const u16* __restrict__ WL0, float* __restrict__ msg0,
    const float* __restrict__ feat1, const float* __restrict__ ef1,
    const int* __restrict__ src1, const u32* __restrict__ perm1,
    const u16* __restrict__ WL1, float* __restrict__ msg1,
    const u32* __restrict__ permS, const u32* __restrict__ stN,
    const u32* __restrict__ hN, const u32* __restrict__ hS,
    float* __restrict__ agg) {
  __shared__ u16 WS[WLN];
  if (blockIdx.x >= 2 * NB) {   // ---- agg-gather blocks ----
    int gid = (blockIdx.x - 2 * NB) * 512 + threadIdx.x;   // 625*512 = 320000
    int m = gid >> 4;
    if (m >= N_NET) return;
    int p = gid & 15;
    u32 j0 = stN[m], j1 = j0 + hN[m];
    float ax = 0.f, ay = 0.f;
    for (u32 j = j0; j < j1; ++j) {
      int s = (int)permS[j];
      float ns = rsqrtf(fmaxf((float)hS[s], 1.0f));
      float2 nf = *(const float2*)(feat1 + (size_t)s * 32 + p * 2);  // node_feat
      ax += ns * nf.x; ay += ns * nf.y;
    }
    *(float2*)(agg + (size_t)m * 32 + p * 2) = make_float2(ax, ay);
    return;
  }
  bool rel = blockIdx.x >= NB;
  int b = rel ? blockIdx.x - NB : blockIdx.x;
  const float* feat = rel ? feat1 : feat0;
  const float* ef   = rel ? ef1 : ef0;
  const int* srcp   = rel ? src1 : src0;
  const u32* perm   = rel ? perm1 : perm0;
  const u16* WLg    = rel ? WL1 : WL0;
  float* msg        = rel ? msg1 : msg0;

  for (int t = threadIdx.x; t < WLN / 8; t += 512)
    ((uint4*)WS)[t] = ((const uint4*)WLg)[t];
  __syncthreads();

  int w = threadIdx.x >> 6, lane = threadIdx.x & 63;
  int er = lane & 15, kg = lane >> 4;

#pragma unroll
  for (int it = 0; it < 2; ++it) {
    int tt = b * 16 + w * 2 + it;          // 16 tiles per block, 2 per wave
    if (tt >= 9375) continue;              // 150000/16 = 9375 exact tiles
    int e0 = tt * 16;
    int e = (int)perm[e0 + er];            // this lane's edge (dst-sorted order)
    int s = srcp[e];
    const float* fp = feat + (size_t)s * 32 + kg * 8;
    float4 f0 = *(const float4*)fp;
    float4 f1 = *(const float4*)(fp + 4);
    float4 pq = *(const float4*)(ef + (size_t)e * 16 + kg * 4);  // pf[er, kg*4..+4]
    f32x4 a0 = {0.f, 0.f, 0.f, 0.f}, a1 = {0.f, 0.f, 0.f, 0.f};
#pragma unroll
    for (int c = 0; c < 16; ++c) {
      int srcl = er + 16 * (c >> 2);
      float pc = (c & 3) == 0 ? pq.x : (c & 3) == 1 ? pq.y : (c & 3) == 2 ? pq.z : pq.w;
      float pv = __shfl(pc, srcl, 64);     // = pf[tile-row er, c]
      u32 d0, d1, d2, d3;
      asm("v_cvt_pk_bf16_f32 %0, %1, %2" : "=v"(d0) : "v"(pv * f0.x), "v"(pv * f0.y));
      asm("v_cvt_pk_bf16_f32 %0, %1, %2" : "=v"(d1) : "v"(pv * f0.z), "v"(pv * f0.w));
      asm("v_cvt_pk_bf16_f32 %0, %1, %2" : "=v"(d2) : "v"(pv * f1.x), "v"(pv * f1.y));
      asm("v_cvt_pk_bf16_f32 %0, %1, %2" : "=v"(d3) : "v"(pv * f1.z), "v"(pv * f1.w));
      short8v af;
      ((u32*)&af)[0] = d0; ((u32*)&af)[1] = d1; ((u32*)&af)[2] = d2; ((u32*)&af)[3] = d3;
      short8v b0 = *(const short8v*)(WS + (c * 2 + 0) * 512 + lane * 8);
      short8v b1 = *(const short8v*)(WS + (c * 2 + 1) * 512 + lane * 8);
      a0 = __builtin_amdgcn_mfma_f32_16x16x32_bf16(af, b0, a0, 0, 0, 0);
      a1 = __builtin_amdgcn_mfma_f32_16x16x32_bf16(af, b1, a1, 0, 0, 0);
    }
    {  // bias step c=16: A = feat (pf == 1)
      u32 d0, d1, d2, d3;
      asm("v_cvt_pk_bf16_f32 %0, %1, %2" : "=v"(d0) : "v"(f0.x), "v"(f0.y));
      asm("v_cvt_pk_bf16_f32 %0, %1, %2" : "=v"(d1) : "v"(f0.z), "v"(f0.w));
      asm("v_cvt_pk_bf16_f32 %0, %1, %2" : "=v"(d2) : "v"(f1.x), "v"(f1.y));
      asm("v_cvt_pk_bf16_f32 %0, %1, %2" : "=v"(d3) : "v"(f1.z), "v"(f1.w));
      short8v af;
      ((u32*)&af)[0] = d0; ((u32*)&af)[1] = d1; ((u32*)&af)[2] = d2; ((u32*)&af)[3] = d3;
      short8v b0 = *(const short8v*)(WS + 32 * 512 + lane * 8);
      short8v b1 = *(const short8v*)(WS + 33 * 512 + lane * 8);
      a0 = __builtin_amdgcn_mfma_f32_16x16x32_bf16(af, b0, a0, 0, 0, 0);
      a1 = __builtin_amdgcn_mfma_f32_16x16x32_bf16(af, b1, a1, 0, 0, 0);
    }
#pragma unroll
    for (int r = 0; r < 4; ++r) {
      int pos = e0 + kg * 4 + r;           // sorted position of this row
      *(float2*)(msg + (size_t)pos * 32 + er * 2) = make_float2(a0[r], a1[r]);
    }
  }
}

// Blocks [0,2500): net_out = rsqrt(max(deg,1))*(agg @ gc_w) + gc_b.
// Blocks [2500,7500): fused segmented mean + bias + max over contiguous
// per-node message runs (16 threads/node own output pairs, 128B rows).
__global__ __launch_bounds__(256) void out_kernel(
    const float* __restrict__ agg, const u32* __restrict__ hN,
    const float* __restrict__ gc_w, const float* __restrict__ gc_b,
    const float* __restrict__ msg_p, const float* __restrict__ msg_n,
    const u32* __restrict__ stP, const u32* __restrict__ hP,
    const u32* __restrict__ stNr, const u32* __restrict__ hNr,
    const float* __restrict__ pinned_b, const float* __restrict__ near_b,
    float* __restrict__ out) {
  if (blockIdx.x < 2500) {
    int gid = blockIdx.x * 256 + threadIdx.x;
    int m = gid >> 5, o = gid & 31;
    float nd = rsqrtf(fmaxf((float)hN[m], 1.0f));
    const float* ag = agg + (size_t)m * 32;
    float a = 0.f;
#pragma unroll
    for (int j = 0; j < 32; ++j) a += ag[j] * gc_w[j * 32 + o];
    out[(size_t)N_NODE * 32 + (size_t)m * 32 + o] = a * nd + gc_b[o];
  } else {
    int gid = (blockIdx.x - 2500) * 256 + threadIdx.x;   // N_NODE*16
    int v = gid >> 4, p = gid & 15;
    u32 a0 = stP[v], dp = hP[v];
    float px = 0.f, py = 0.f;
    for (u32 j = a0; j < a0 + dp; ++j) {
      float2 mm = *(const float2*)(msg_p + (size_t)j * 32 + p * 2);
      px += mm.x; py += mm.y;
    }
    float idp = 1.0f / fmaxf((float)dp, 1.0f);
    u32 b0 = stNr[v], dn = hNr[v];
    float nx = 0.f, ny = 0.f;
    for (u32 j = b0; j < b0 + dn; ++j) {
      float2 mm = *(const float2*)(msg_n + (size_t)j * 32 + p * 2);
      nx += mm.x; ny += mm.y;
    }
    float idn = 1.0f / fmaxf((float)dn, 1.0f);
    float2 r;
    r.x = fmaxf(px * idp + pinned_b[2 * p],     nx * idn + near_b[2 * p]);
    r.y = fmaxf(py * idp + pinned_b[2 * p + 1], ny * idn + near_b[2 * p + 1]);
    *(float2*)(out + (size_t)v * 32 + p * 2) = r;
  }
}

extern "C" void kernel_launch(void* const* d_in, const int* in_sizes, int n_in,
                              void* d_out, int out_size, void* d_ws, size_t ws_size,
                              hipStream_t stream) {
  const float* node_feat = (const float*)d_in[0];
  const float* net_feat  = (const float*)d_in[1];
  const float* pin_feat  = (const float*)d_in[2];
  const float* edge_feat = (const float*)d_in[3];
  const float* topo_w    = (const float*)d_in[4];
  const float* topo_b    = (const float*)d_in[5];
  const float* geom_w    = (const float*)d_in[6];
  const float* geom_b    = (const float*)d_in[7];
  const float* gc_w      = (const float*)d_in[8];
  const float* gc_b      = (const float*)d_in[9];
  const float* pinned_b  = (const float*)d_in[10];
  const float* near_b    = (const float*)d_in[11];
  const int* pins_src    = (const int*)d_in[12];
  const int* pins_dst    = (const int*)d_in[13];
  const int* pinned_src  = (const int*)d_in[14];
  const int* pinned_dst  = (const int*)d_in[15];
  const int* near_src    = (const int*)d_in[16];
  const int* near_dst    = (const int*)d_in[17];

  char* ws = (char*)d_ws;
  float* msg_p = (float*)ws;                 // 4,800,000 f32 (19.2 MB)
  float* msg_n = msg_p + 4800000;            // 4,800,000
  float* agg   = msg_n + 4800000;            //   640,000
  u32* hN   = (u32*)(agg + 640000);          //  20,000  -- zero region start
  u32* hP   = hN + 20000;                    //  80,000
  u32* hNr  = hP + 80000;                    //  80,000
  u32* hS   = hNr + 80000;                   //  80,000
  u32* cnt  = hS + 80000;                    //       4  -- zero region end
  u32* stN  = cnt + 4;                       //  20,000
  u32* stP  = stN + 20000;                   //  80,000
  u32* stNr = stP + 80000;                   //  80,000
  u32* curN = stNr + 80000;                  //  20,000
  u32* curP = curN + 20000;                  //  80,000
  u32* curNr= curP + 80000;                  //  80,000
  u32* permS= curNr + 80000;                 // 150,000
  u32* permP= permS + 150000;                // 150,000
  u32* permN= permP + 150000;                // 150,000
  u16* WL0 = (u16*)(permN + 150000);         // 16B-aligned (all counts %4==0)
  u16* WL1 = WL0 + WLN;

  hipMemsetAsync(hN, 0, (size_t)260004 * 4, stream);   // 4 histograms + counters
  prep_kernel<<<722, 256, 0, stream>>>(topo_w, topo_b, geom_w, geom_b, WL0, WL1,
                                       pins_src, pins_dst, pinned_dst, near_dst,
                                       hN, hP, hNr, hS);
  alloc_kernel<<<705, 256, 0, stream>>>(hN, stN, curN, hP, stP, curP,
                                        hNr, stNr, curNr, cnt);
  perm_kernel<<<3 * NB, 256, 0, stream>>>(pins_src, pins_dst, pinned_dst, near_dst,
                                          curN, curP, curNr, permS, permP, permN);
  nnconv_agg_kernel<<<2 * NB + 625, 512, 0, stream>>>(
      net_feat,  pin_feat,  pinned_src, permP, WL0, msg_p,
      node_feat, edge_feat, near_src,   permN, WL1, msg_n,
      permS, stN, hN, hS, agg);
  out_kernel<<<7500, 256, 0, stream>>>(agg, hN, gc_w, gc_b, msg_p, msg_n,
                                       stP, hP, stNr, hNr,
                                       pinned_b, near_b, (float*)d_out);
}